// Round 2
// baseline (745.419 us; speedup 1.0000x reference)
//
#include <hip/hip_runtime.h>

typedef unsigned short u16;
typedef __bf16 bf16x8 __attribute__((ext_vector_type(8)));
typedef float f32x4 __attribute__((ext_vector_type(4)));
typedef int i32x4 __attribute__((ext_vector_type(4)));

__device__ inline u16 f2bf(float f) {
  union { float f; unsigned u; } v; v.f = f;
  unsigned u = v.u;
  unsigned r = (u + 0x7FFFu + ((u >> 16) & 1u)) >> 16;
  return (u16)r;
}

__device__ inline float gelu_f(float x) {
  // tanh approximation (jax.nn.gelu default), overflow-safe tanh
  float t = 0.7978845608028654f * (x + 0.044715f * x * x * x);
  float a = __expf(-2.f * fabsf(t));
  float th = (1.f - a) / (1.f + a);
  th = copysignf(th, t);
  return 0.5f * x * (1.f + th);
}
__device__ inline float sigmoid_f(float x) { return 1.f / (1.f + __expf(-x)); }

// async global->LDS, 16B per lane; LDS dest is wave-uniform base + lane*16 (m104)
__device__ __forceinline__ void gld16(const u16* g, u16* l) {
  __builtin_amdgcn_global_load_lds((const __attribute__((address_space(1))) void*)g,
                                   (__attribute__((address_space(3))) void*)l, 16, 0, 0);
}

// ---------------- transpose + fp32->bf16 convert: out[c][r] = in[r][c] ----------------
__global__ void transpose_cvt(const float* __restrict__ in, u16* __restrict__ out,
                              int R, int C, int ldout) {
  __shared__ float tile[32][33];
  int c0 = blockIdx.x * 32, r0 = blockIdx.y * 32;
  int tx = threadIdx.x, ty = threadIdx.y;
#pragma unroll
  for (int i = 0; i < 32; i += 8) {
    int r = r0 + ty + i, c = c0 + tx;
    tile[ty + i][tx] = (r < R && c < C) ? in[(long)r * C + c] : 0.f;
  }
  __syncthreads();
#pragma unroll
  for (int i = 0; i < 32; i += 8) {
    int cc = c0 + ty + i, rr = r0 + tx;
    if (cc < C && rr < R) out[(long)cc * ldout + rr] = f2bf(tile[tx][ty + i]);
  }
}

// ---------------- RMSNorm (D=1024 fixed), fp32 in -> bf16 out ----------------
__global__ __launch_bounds__(256) void rmsnorm_k(const float* __restrict__ x,
                                                 const float* __restrict__ w,
                                                 u16* __restrict__ out) {
  int row = blockIdx.x;
  int tid = threadIdx.x;
  const float4* xv = (const float4*)(x + (long)row * 1024);
  float4 v = xv[tid];
  float ss = v.x * v.x + v.y * v.y + v.z * v.z + v.w * v.w;
#pragma unroll
  for (int off = 32; off > 0; off >>= 1) ss += __shfl_down(ss, off);
  __shared__ float red[4];
  if ((tid & 63) == 0) red[tid >> 6] = ss;
  __syncthreads();
  float tot = red[0] + red[1] + red[2] + red[3];
  float scale = rsqrtf(tot * (1.f / 1024.f) + 1e-6f);
  const float4* wv4 = (const float4*)w;
  float4 wv = wv4[tid];
  ushort4 o;
  o.x = f2bf(v.x * wv.x * scale);
  o.y = f2bf(v.y * wv.y * scale);
  o.z = f2bf(v.z * wv.z * scale);
  o.w = f2bf(v.w * wv.w * scale);
  *((ushort4*)(out + (long)row * 1024) + tid) = o;
}

// ---------------- generic bf16 GEMM, C = A(MxK) * Bt(NxK)^T, 128x128x64 tiles ----------------
// m97 structure: global_load_lds w16 staging, linear LDS, single-buffered 2-barrier loop.
// gridDim.z = split-K factor (partials via EPI_PART). XCD swizzle when nwg%8==0.
#define EPI_BF16 0
#define EPI_ROUTE1 1
#define EPI_ADD_BF16 2
#define EPI_ADD_F32 3
#define EPI_GELU_BF16 4
#define EPI_PART 5

template <int EPI>
__global__ __launch_bounds__(256) void gemm_bt(
    const u16* __restrict__ A, const u16* __restrict__ Bt,
    u16* __restrict__ obf, float* __restrict__ of32, const float* __restrict__ add,
    float* __restrict__ og, float* __restrict__ ofl,
    int N, int K, int lda, int ldb) {
  __shared__ __align__(16) u16 As[128 * 64];
  __shared__ __align__(16) u16 Bs[128 * 64];
  const int tid = threadIdx.x;
  const int lane = tid & 63;
  const int wave = tid >> 6;

  // XCD-aware swizzle over the full linear block id (T1); identity if nwg%8!=0
  const int gx = gridDim.x, gy = gridDim.y, gz = gridDim.z;
  const int nwg = gx * gy * gz;
  int orig = (blockIdx.z * gy + blockIdx.y) * gx + blockIdx.x;
  int id = ((nwg & 7) == 0) ? ((orig & 7) * (nwg >> 3) + (orig >> 3)) : orig;
  const int bx = id % gx;
  const int by = (id / gx) % gy;
  const int bz = id / (gx * gy);

  const int wm = wave >> 1, wn = wave & 1;
  const int bm0 = by * 128, bn0 = bx * 128;
  const int kper = K / gz;
  const int koff = bz * kper;

  f32x4 acc[4][4];
  f32x4 zero = {0.f, 0.f, 0.f, 0.f};
#pragma unroll
  for (int m = 0; m < 4; ++m)
#pragma unroll
    for (int n = 0; n < 4; ++n) acc[m][n] = zero;

  // staging map: wave w, iter j covers rows j*32 + w*8 .. +8; lane l -> row +(l>>3), 16B chunk l&7
  const int lrow = lane >> 3, lchk = lane & 7;
  const long abase = (long)(bm0 + wave * 8 + lrow) * lda + koff + lchk * 8;
  const long bbase = (long)(bn0 + wave * 8 + lrow) * ldb + koff + lchk * 8;

  const int nk = kper >> 6;
  for (int t = 0; t < nk; ++t) {
    const int k0 = t << 6;
#pragma unroll
    for (int j = 0; j < 4; ++j) {
      gld16(A + abase + (long)j * 32 * lda + k0, &As[(wave * 8 + j * 32) * 64]);
      gld16(Bt + bbase + (long)j * 32 * ldb + k0, &Bs[(wave * 8 + j * 32) * 64]);
    }
    __syncthreads();  // drains vmcnt -> staged data visible
#pragma unroll
    for (int kk = 0; kk < 2; ++kk) {
      bf16x8 av[4], bv[4];
#pragma unroll
      for (int m = 0; m < 4; ++m) {
        int r = wm * 64 + m * 16 + (lane & 15);
        int c = kk * 4 + (lane >> 4);
        av[m] = __builtin_bit_cast(bf16x8, *(const i32x4*)&As[r * 64 + c * 8]);
      }
#pragma unroll
      for (int n = 0; n < 4; ++n) {
        int r = wn * 64 + n * 16 + (lane & 15);
        int c = kk * 4 + (lane >> 4);
        bv[n] = __builtin_bit_cast(bf16x8, *(const i32x4*)&Bs[r * 64 + c * 8]);
      }
#pragma unroll
      for (int m = 0; m < 4; ++m)
#pragma unroll
        for (int n = 0; n < 4; ++n)
          acc[m][n] = __builtin_amdgcn_mfma_f32_16x16x32_bf16(av[m], bv[n], acc[m][n], 0, 0, 0);
    }
    __syncthreads();  // protect LDS before next stage overwrites
  }

  // epilogue: C/D layout col=lane&15, row=(lane>>4)*4+reg (m89-verified)
#pragma unroll
  for (int m = 0; m < 4; ++m) {
    int row_b = bm0 + wm * 64 + m * 16 + ((lane >> 4) << 2);
#pragma unroll
    for (int n = 0; n < 4; ++n) {
      int col = bn0 + wn * 64 + n * 16 + (lane & 15);
#pragma unroll
      for (int j = 0; j < 4; ++j) {
        int row = row_b + j;
        float v = acc[m][n][j];
        if constexpr (EPI == EPI_BF16) {
          obf[(long)row * N + col] = f2bf(v);
        } else if constexpr (EPI == EPI_ROUTE1) {
          if (col < 512) of32[(long)row * 512 + col] = v;                       // pre_path -> t
          else if (col < 2560) og[(long)row * 2048 + (col - 512)] = gelu_f(v);  // gelu(U)
          else ofl[(long)row * 512 + (col - 2560)] = sigmoid_f(v);              // F gate
        } else if constexpr (EPI == EPI_ADD_BF16) {
          long idx = (long)row * N + col;
          obf[idx] = f2bf(add[idx] + v);
        } else if constexpr (EPI == EPI_ADD_F32) {
          long idx = (long)row * N + col;
          of32[idx] = add[idx] + v;
        } else if constexpr (EPI == EPI_GELU_BF16) {
          obf[(long)row * N + col] = f2bf(gelu_f(v));
        } else {  // EPI_PART: split-K partial, plane bz
          of32[(long)bz * 4096 * N + (long)row * N + col] = v;
        }
      }
    }
  }
}

// ---------------- split-K reduce: o = base + p0 + p1 (4096x1024 f32) ----------------
__global__ __launch_bounds__(256) void reduce2_k(const float* __restrict__ base,
                                                 const float* __restrict__ p0,
                                                 const float* __restrict__ p1,
                                                 float* __restrict__ o) {
  long i = (long)blockIdx.x * 256 + threadIdx.x;  // float4 index
  float4 b = ((const float4*)base)[i];
  float4 q0 = ((const float4*)p0)[i];
  float4 q1 = ((const float4*)p1)[i];
  float4 r;
  r.x = b.x + q0.x + q1.x;
  r.y = b.y + q0.y + q1.y;
  r.z = b.z + q0.z + q1.z;
  r.w = b.w + q0.w + q1.w;
  ((float4*)o)[i] = r;
}

// ---------------- router: t += sum_a gelu(U)[.., a*512+p] ----------------
__global__ __launch_bounds__(256) void router_k(float* __restrict__ tb, const float* __restrict__ G) {
  int i = blockIdx.x * 256 + threadIdx.x;  // float4 index over 4096x512
  int r = i >> 7, pq = i & 127;
  float4 t = ((float4*)tb)[i];
#pragma unroll
  for (int a = 0; a < 4; ++a) {
    float4 g = *((const float4*)(G + (long)r * 2048 + a * 512) + pq);
    t.x += g.x; t.y += g.y; t.z += g.z; t.w += g.w;
  }
  ((float4*)tb)[i] = t;
}

// ---------------- chunk-parallel affine scan: h_t = f_t*h_{t-1} + u_t ----------------
__global__ void scan_chunk(const float* __restrict__ tb, const float* __restrict__ F,
                           float* __restrict__ abuf, float* __restrict__ ubuf) {
  int b = blockIdx.x >> 5, c = blockIdx.x & 31, pidx = threadIdx.x;
  const float* fp = F + ((long)(b * 2048 + c * 64) * 512) + pidx;
  const float* up = tb + ((long)(b * 2048 + c * 64) * 512) + pidx;
  float A = 1.f, U = 0.f;
#pragma unroll 8
  for (int s = 0; s < 64; ++s) {
    float f = fp[(long)s * 512], u = up[(long)s * 512];
    A = f * A;
    U = f * U + u;
  }
  abuf[(b * 32 + c) * 512 + pidx] = A;
  ubuf[(b * 32 + c) * 512 + pidx] = U;
}

__global__ void scan_combine(const float* __restrict__ abuf, const float* __restrict__ ubuf,
                             float* __restrict__ hstart) {
  int b = blockIdx.x, pidx = threadIdx.x;
  float h = 0.f;
  for (int c = 0; c < 32; ++c) {
    hstart[(b * 32 + c) * 512 + pidx] = h;
    h = abuf[(b * 32 + c) * 512 + pidx] * h + ubuf[(b * 32 + c) * 512 + pidx];
  }
}

__global__ void scan_apply(const float* __restrict__ tb, const float* __restrict__ F,
                           const float* __restrict__ hstart, u16* __restrict__ hbf) {
  int b = blockIdx.x >> 5, c = blockIdx.x & 31, pidx = threadIdx.x;
  const float* fp = F + ((long)(b * 2048 + c * 64) * 512) + pidx;
  const float* up = tb + ((long)(b * 2048 + c * 64) * 512) + pidx;
  u16* op = hbf + ((long)(b * 2048 + c * 64) * 512) + pidx;
  float h = hstart[(b * 32 + c) * 512 + pidx];
#pragma unroll 8
  for (int s = 0; s < 64; ++s) {
    float f = fp[(long)s * 512], u = up[(long)s * 512];
    h = f * h + u;
    op[(long)s * 512] = f2bf(h);
  }
}

extern "C" void kernel_launch(void* const* d_in, const int* in_sizes, int n_in,
                              void* d_out, int out_size, void* d_ws, size_t ws_size,
                              hipStream_t stream) {
  const float* x       = (const float*)d_in[0];
  const float* w_norm1 = (const float*)d_in[1];
  const float* w_toP   = (const float*)d_in[2];
  const float* w_emb   = (const float*)d_in[3];
  const float* w_f     = (const float*)d_in[4];
  const float* b_r     = (const float*)d_in[5];
  const float* c_r     = (const float*)d_in[6];
  const float* w_fromP = (const float*)d_in[7];
  const float* w_norm2 = (const float*)d_in[8];
  const float* w_fc1   = (const float*)d_in[9];
  const float* w_fc2   = (const float*)d_in[10];
  float* out = (float*)d_out;

  char* base = (char*)d_ws;
  size_t off = 0;
  auto alloc = [&](size_t bytes) {
    void* r = base + off;
    off += (bytes + 255) & ~(size_t)255;
    return r;
  };
  u16* W1T     = (u16*)alloc((size_t)3072 * 1024 * 2);   // [w_toP|w_emb|w_f]^T  (3072 x 1024)
  u16* WfromPT = (u16*)alloc((size_t)1024 * 512 * 2);    // w_fromP^T (1024 x 512)
  u16* Wfc1T   = (u16*)alloc((size_t)16384 * 1024 * 2);  // w_fc1^T (16384 x 1024)
  u16* Wfc2T   = (u16*)alloc((size_t)1024 * 16384 * 2);  // w_fc2^T (1024 x 16384)
  u16* BrT     = (u16*)alloc((size_t)128 * 512 * 2);     // b_r^T padded to 128 rows
  u16* CrT     = (u16*)alloc((size_t)512 * 128 * 2);     // c_r^T padded to 128 cols
  u16* h1      = (u16*)alloc((size_t)4096 * 1024 * 2);
  float* G     = (float*)alloc((size_t)4096 * 2048 * 4);  // gelu(U); reused as split-K partials in MLP
  float* F     = (float*)alloc((size_t)4096 * 512 * 4);
  float* tb    = (float*)alloc((size_t)4096 * 512 * 4);
  float* abuf  = (float*)alloc((size_t)2 * 32 * 512 * 4);
  float* ubuf  = (float*)alloc((size_t)2 * 32 * 512 * 4);
  float* hstart= (float*)alloc((size_t)2 * 32 * 512 * 4);
  u16* hbf     = (u16*)alloc((size_t)4096 * 512 * 2);
  u16* g1buf   = (u16*)alloc((size_t)4096 * 128 * 2);
  u16* tt      = (u16*)alloc((size_t)4096 * 512 * 2);
  float* xmid  = (float*)alloc((size_t)4096 * 1024 * 4);
  u16* h2      = (u16*)alloc((size_t)4096 * 1024 * 2);
  u16* a3      = (u16*)alloc((size_t)4096 * 4096 * 2);
  (void)ws_size; (void)in_sizes; (void)n_in; (void)out_size;

  dim3 tpb(32, 8);
  // weight transposes + bf16 convert
  transpose_cvt<<<dim3(16, 32), tpb, 0, stream>>>(w_toP, W1T, 1024, 512, 1024);
  transpose_cvt<<<dim3(64, 32), tpb, 0, stream>>>(w_emb, W1T + (size_t)512 * 1024, 1024, 2048, 1024);
  transpose_cvt<<<dim3(16, 32), tpb, 0, stream>>>(w_f, W1T + (size_t)2560 * 1024, 1024, 512, 1024);
  transpose_cvt<<<dim3(32, 16), tpb, 0, stream>>>(w_fromP, WfromPT, 512, 1024, 512);
  transpose_cvt<<<dim3(512, 32), tpb, 0, stream>>>(w_fc1, Wfc1T, 1024, 16384, 1024);
  transpose_cvt<<<dim3(32, 512), tpb, 0, stream>>>(w_fc2, Wfc2T, 16384, 1024, 16384);
  hipMemsetAsync(BrT, 0, (size_t)128 * 512 * 2, stream);
  hipMemsetAsync(CrT, 0, (size_t)512 * 128 * 2, stream);
  transpose_cvt<<<dim3(2, 16), tpb, 0, stream>>>(b_r, BrT, 512, 64, 512);
  transpose_cvt<<<dim3(16, 2), tpb, 0, stream>>>(c_r, CrT, 64, 512, 128);

  // h1 = rmsnorm(x, w_norm1)
  rmsnorm_k<<<4096, 256, 0, stream>>>(x, w_norm1, h1);

  // fused GEMM1: [pre | gelu(U) | sigmoid(F)] = h1 @ [w_toP|w_emb|w_f]
  gemm_bt<EPI_ROUTE1><<<dim3(24, 32), 256, 0, stream>>>(h1, W1T, nullptr, tb, nullptr, G, F,
                                                        3072, 1024, 1024, 1024);
  // t = pre + sum_a gelu(U_a)
  router_k<<<2048, 256, 0, stream>>>(tb, G);

  // SSM scan -> h (bf16)
  scan_chunk<<<64, 512, 0, stream>>>(tb, F, abuf, ubuf);
  scan_combine<<<2, 512, 0, stream>>>(abuf, ubuf, hstart);
  scan_apply<<<64, 512, 0, stream>>>(tb, F, hstart, hbf);

  // low-rank: g1 = h @ b_r (padded N=128), t_tilde = t + g1 @ c_r
  gemm_bt<EPI_BF16><<<dim3(1, 32), 256, 0, stream>>>(hbf, BrT, g1buf, nullptr, nullptr, nullptr, nullptr,
                                                     128, 512, 512, 512);
  gemm_bt<EPI_ADD_BF16><<<dim3(4, 32), 256, 0, stream>>>(g1buf, CrT, tt, nullptr, tb, nullptr, nullptr,
                                                         512, 128, 128, 128);
  // xmid = x + t_tilde @ w_fromP
  gemm_bt<EPI_ADD_F32><<<dim3(8, 32), 256, 0, stream>>>(tt, WfromPT, nullptr, xmid, x, nullptr, nullptr,
                                                        1024, 512, 512, 512);
  // h2 = rmsnorm(xmid, w_norm2)
  rmsnorm_k<<<4096, 256, 0, stream>>>(xmid, w_norm2, h2);

  // MLP in 4 HID-chunks: a3 = gelu(h2 @ fc1_chunk); out = base + splitK partials of a3 @ fc2_chunk
  float* p0 = G;
  float* p1 = G + (size_t)4096 * 1024;
  for (int c = 0; c < 4; ++c) {
    gemm_bt<EPI_GELU_BF16><<<dim3(32, 32), 256, 0, stream>>>(
        h2, Wfc1T + (size_t)c * 4096 * 1024, a3, nullptr, nullptr, nullptr, nullptr,
        4096, 1024, 1024, 1024);
    gemm_bt<EPI_PART><<<dim3(8, 32, 2), 256, 0, stream>>>(
        a3, Wfc2T + (size_t)c * 4096, nullptr, p0, nullptr, nullptr, nullptr,
        1024, 4096, 4096, 16384);
    reduce2_k<<<4096, 256, 0, stream>>>((c == 0 ? xmid : out), p0, p1, out);
  }
}

// Round 3
// 658.658 us; speedup vs baseline: 1.1317x; 1.1317x over previous
//
#include <hip/hip_runtime.h>

typedef unsigned short u16;
typedef __bf16 bf16x8 __attribute__((ext_vector_type(8)));
typedef float f32x4 __attribute__((ext_vector_type(4)));
typedef int i32x4 __attribute__((ext_vector_type(4)));

__device__ inline u16 f2bf(float f) {
  union { float f; unsigned u; } v; v.f = f;
  unsigned u = v.u;
  unsigned r = (u + 0x7FFFu + ((u >> 16) & 1u)) >> 16;
  return (u16)r;
}

__device__ inline float gelu_f(float x) {
  // tanh approximation (jax.nn.gelu default), overflow-safe tanh
  float t = 0.7978845608028654f * (x + 0.044715f * x * x * x);
  float a = __expf(-2.f * fabsf(t));
  float th = (1.f - a) / (1.f + a);
  th = copysignf(th, t);
  return 0.5f * x * (1.f + th);
}
__device__ inline float sigmoid_f(float x) { return 1.f / (1.f + __expf(-x)); }

// async global->LDS, 16B per lane; LDS dest is wave-uniform base + lane*16 (m104)
__device__ __forceinline__ void gld16(const u16* g, u16* l) {
  __builtin_amdgcn_global_load_lds((const __attribute__((address_space(1))) void*)g,
                                   (__attribute__((address_space(3))) void*)l, 16, 0, 0);
}

// ---------------- transpose + fp32->bf16 convert: out[c][r] = in[r][c] ----------------
__global__ void transpose_cvt(const float* __restrict__ in, u16* __restrict__ out,
                              int R, int C, int ldout) {
  __shared__ float tile[32][33];
  int c0 = blockIdx.x * 32, r0 = blockIdx.y * 32;
  int tx = threadIdx.x, ty = threadIdx.y;
#pragma unroll
  for (int i = 0; i < 32; i += 8) {
    int r = r0 + ty + i, c = c0 + tx;
    tile[ty + i][tx] = (r < R && c < C) ? in[(long)r * C + c] : 0.f;
  }
  __syncthreads();
#pragma unroll
  for (int i = 0; i < 32; i += 8) {
    int cc = c0 + ty + i, rr = r0 + tx;
    if (cc < C && rr < R) out[(long)cc * ldout + rr] = f2bf(tile[tx][ty + i]);
  }
}

// ---------------- RMSNorm (D=1024 fixed), fp32 in -> bf16 out ----------------
__global__ __launch_bounds__(256) void rmsnorm_k(const float* __restrict__ x,
                                                 const float* __restrict__ w,
                                                 u16* __restrict__ out) {
  int row = blockIdx.x;
  int tid = threadIdx.x;
  const float4* xv = (const float4*)(x + (long)row * 1024);
  float4 v = xv[tid];
  float ss = v.x * v.x + v.y * v.y + v.z * v.z + v.w * v.w;
#pragma unroll
  for (int off = 32; off > 0; off >>= 1) ss += __shfl_down(ss, off);
  __shared__ float red[4];
  if ((tid & 63) == 0) red[tid >> 6] = ss;
  __syncthreads();
  float tot = red[0] + red[1] + red[2] + red[3];
  float scale = rsqrtf(tot * (1.f / 1024.f) + 1e-6f);
  const float4* wv4 = (const float4*)w;
  float4 wv = wv4[tid];
  ushort4 o;
  o.x = f2bf(v.x * wv.x * scale);
  o.y = f2bf(v.y * wv.y * scale);
  o.z = f2bf(v.z * wv.z * scale);
  o.w = f2bf(v.w * wv.w * scale);
  *((ushort4*)(out + (long)row * 1024) + tid) = o;
}

#define EPI_BF16 0
#define EPI_ROUTE1 1
#define EPI_ADD_BF16 2
#define EPI_ADD_F32 3
#define EPI_GELU_BF16 4
#define EPI_PART 5

// ---------------- 256x256x64 2-phase dbuf GEMM, 512 threads (8 waves, 2Mx4N) ----------------
// C = A(MxK) * Bt(NxK)^T. LDS 128KiB double-buffered; global_load_lds w16 staging issued
// BEFORE compute each tile (T3-minimum recipe, m230-V0 structure); one barrier per K-tile.
template <int EPI>
__global__ __launch_bounds__(512, 2) void gemm256(
    const u16* __restrict__ A, const u16* __restrict__ Bt,
    u16* __restrict__ obf, float* __restrict__ of32,
    float* __restrict__ og, float* __restrict__ ofl,
    int N, int K, int lda, int ldb) {
  __shared__ __align__(16) u16 sA[2][256 * 64];
  __shared__ __align__(16) u16 sB[2][256 * 64];
  const int tid = threadIdx.x;
  const int lane = tid & 63;
  const int wave = tid >> 6;
  const int wm = wave >> 2, wn = wave & 3;

  // XCD-aware swizzle (T1); identity if nwg%8!=0
  const int gx = gridDim.x, gy = gridDim.y, gz = gridDim.z;
  const int nwg = gx * gy * gz;
  int orig = (blockIdx.z * gy + blockIdx.y) * gx + blockIdx.x;
  int id = ((nwg & 7) == 0) ? ((orig & 7) * (nwg >> 3) + (orig >> 3)) : orig;
  const int bx = id % gx;
  const int by = (id / gx) % gy;
  const int bz = id / (gx * gy);
  const int bm0 = by * 256, bn0 = bx * 256;
  const int kper = K / gz, koff = bz * kper;

  f32x4 acc[8][4];
  f32x4 zero = {0.f, 0.f, 0.f, 0.f};
#pragma unroll
  for (int m = 0; m < 8; ++m)
#pragma unroll
    for (int n = 0; n < 4; ++n) acc[m][n] = zero;

  // staging map: thread t -> row g*64 + (t>>3), 16B chunk (t&7); LDS dest linear (wave-uniform base)
  const int srow = tid >> 3, schk = tid & 7;
  const long abase = (long)(bm0 + srow) * lda + koff + schk * 8;
  const long bbase = (long)(bn0 + srow) * ldb + koff + schk * 8;
  const int ldsw = wave * 8 * 64;  // u16 elements

  const int nk = kper >> 6;
  // prologue: stage tile 0 into buf0
#pragma unroll
  for (int g = 0; g < 4; ++g) {
    gld16(A + abase + (long)g * 64 * lda, &sA[0][g * 64 * 64 + ldsw]);
    gld16(Bt + bbase + (long)g * 64 * ldb, &sB[0][g * 64 * 64 + ldsw]);
  }
  __syncthreads();
  int cur = 0;
  for (int t = 0; t < nk; ++t) {
    if (t + 1 < nk) {  // issue next-tile stage FIRST; lands under this tile's MFMAs
      const long k0 = (long)(t + 1) << 6;
#pragma unroll
      for (int g = 0; g < 4; ++g) {
        gld16(A + abase + (long)g * 64 * lda + k0, &sA[cur ^ 1][g * 64 * 64 + ldsw]);
        gld16(Bt + bbase + (long)g * 64 * ldb + k0, &sB[cur ^ 1][g * 64 * 64 + ldsw]);
      }
    }
#pragma unroll
    for (int kk = 0; kk < 2; ++kk) {
      bf16x8 av[8], bv[4];
      const int c8 = (kk * 4 + (lane >> 4)) * 8;
#pragma unroll
      for (int m = 0; m < 8; ++m)
        av[m] = __builtin_bit_cast(bf16x8,
            *(const i32x4*)&sA[cur][(wm * 128 + m * 16 + (lane & 15)) * 64 + c8]);
#pragma unroll
      for (int n = 0; n < 4; ++n)
        bv[n] = __builtin_bit_cast(bf16x8,
            *(const i32x4*)&sB[cur][(wn * 64 + n * 16 + (lane & 15)) * 64 + c8]);
      __builtin_amdgcn_s_setprio(1);
#pragma unroll
      for (int m = 0; m < 8; ++m)
#pragma unroll
        for (int n = 0; n < 4; ++n)
          acc[m][n] = __builtin_amdgcn_mfma_f32_16x16x32_bf16(av[m], bv[n], acc[m][n], 0, 0, 0);
      __builtin_amdgcn_s_setprio(0);
    }
    __syncthreads();  // drains vmcnt(0)+lgkmcnt(0): next buf ready, this buf's reads done
    cur ^= 1;
  }

  // epilogue: C/D layout col=lane&15, row=(lane>>4)*4+reg (m89-verified)
#pragma unroll
  for (int m = 0; m < 8; ++m) {
    int row_b = bm0 + wm * 128 + m * 16 + ((lane >> 4) << 2);
#pragma unroll
    for (int n = 0; n < 4; ++n) {
      int col = bn0 + wn * 64 + n * 16 + (lane & 15);
#pragma unroll
      for (int j = 0; j < 4; ++j) {
        int row = row_b + j;
        float v = acc[m][n][j];
        if constexpr (EPI == EPI_GELU_BF16) {
          obf[(long)row * N + col] = f2bf(gelu_f(v));
        } else if constexpr (EPI == EPI_ROUTE1) {
          if (col < 512) of32[(long)row * 512 + col] = v;                       // pre_path -> t
          else if (col < 2560) og[(long)row * 2048 + (col - 512)] = gelu_f(v);  // gelu(U)
          else ofl[(long)row * 512 + (col - 2560)] = sigmoid_f(v);              // F gate
        } else {  // EPI_PART: split-K partial plane bz (N==1024)
          of32[(long)bz * (4096L * 1024) + (long)row * N + col] = v;
        }
      }
    }
  }
}

// ---------------- generic bf16 GEMM, 128x128x64 tiles, reg-staged (round-1, known-good) ----
template <int EPI>
__global__ __launch_bounds__(256) void gemm_bt(
    const u16* __restrict__ A, const u16* __restrict__ Bt,
    u16* __restrict__ obf, float* __restrict__ of32, const float* __restrict__ add,
    float* __restrict__ og, float* __restrict__ ofl,
    int N, int K, int lda, int ldb) {
  __shared__ __align__(16) u16 As[128 * 64];
  __shared__ __align__(16) u16 Bs[128 * 64];
  const int tid = threadIdx.x;
  const int lane = tid & 63;
  const int wave = tid >> 6;
  const int wm = wave >> 1, wn = wave & 1;
  const int bm0 = blockIdx.y * 128, bn0 = blockIdx.x * 128;

  f32x4 acc[4][4];
  f32x4 zero = {0.f, 0.f, 0.f, 0.f};
#pragma unroll
  for (int m = 0; m < 4; ++m)
#pragma unroll
    for (int n = 0; n < 4; ++n) acc[m][n] = zero;

  i32x4 ra[4], rb[4];
  int srow[4], schk[4];
#pragma unroll
  for (int i = 0; i < 4; ++i) {
    int s = tid + 256 * i;
    srow[i] = s >> 3;
    schk[i] = s & 7;
  }
#pragma unroll
  for (int i = 0; i < 4; ++i) {
    ra[i] = *(const i32x4*)(A + (bm0 + srow[i]) * lda + schk[i] * 8);
    rb[i] = *(const i32x4*)(Bt + (bn0 + srow[i]) * ldb + schk[i] * 8);
  }

  const int nk = K >> 6;
  for (int t = 0; t < nk; ++t) {
#pragma unroll
    for (int i = 0; i < 4; ++i) {
      *(i32x4*)&As[srow[i] * 64 + ((schk[i] ^ (srow[i] & 7)) << 3)] = ra[i];
      *(i32x4*)&Bs[srow[i] * 64 + ((schk[i] ^ (srow[i] & 7)) << 3)] = rb[i];
    }
    __syncthreads();
    if (t + 1 < nk) {
      int k0 = (t + 1) << 6;
#pragma unroll
      for (int i = 0; i < 4; ++i) {
        ra[i] = *(const i32x4*)(A + (bm0 + srow[i]) * lda + k0 + schk[i] * 8);
        rb[i] = *(const i32x4*)(Bt + (bn0 + srow[i]) * ldb + k0 + schk[i] * 8);
      }
    }
#pragma unroll
    for (int kk = 0; kk < 2; ++kk) {
      bf16x8 av[4], bv[4];
#pragma unroll
      for (int m = 0; m < 4; ++m) {
        int r = wm * 64 + m * 16 + (lane & 15);
        int c = kk * 4 + (lane >> 4);
        av[m] = __builtin_bit_cast(bf16x8, *(const i32x4*)&As[r * 64 + ((c ^ (r & 7)) << 3)]);
      }
#pragma unroll
      for (int n = 0; n < 4; ++n) {
        int r = wn * 64 + n * 16 + (lane & 15);
        int c = kk * 4 + (lane >> 4);
        bv[n] = __builtin_bit_cast(bf16x8, *(const i32x4*)&Bs[r * 64 + ((c ^ (r & 7)) << 3)]);
      }
#pragma unroll
      for (int m = 0; m < 4; ++m)
#pragma unroll
        for (int n = 0; n < 4; ++n)
          acc[m][n] = __builtin_amdgcn_mfma_f32_16x16x32_bf16(av[m], bv[n], acc[m][n], 0, 0, 0);
    }
    __syncthreads();
  }

#pragma unroll
  for (int m = 0; m < 4; ++m) {
    int row_b = bm0 + wm * 64 + m * 16 + ((lane >> 4) << 2);
#pragma unroll
    for (int n = 0; n < 4; ++n) {
      int col = bn0 + wn * 64 + n * 16 + (lane & 15);
#pragma unroll
      for (int j = 0; j < 4; ++j) {
        int row = row_b + j;
        float v = acc[m][n][j];
        if constexpr (EPI == EPI_BF16) {
          obf[(long)row * N + col] = f2bf(v);
        } else if constexpr (EPI == EPI_ADD_BF16) {
          long idx = (long)row * N + col;
          obf[idx] = f2bf(add[idx] + v);
        } else if constexpr (EPI == EPI_ADD_F32) {
          long idx = (long)row * N + col;
          of32[idx] = add[idx] + v;
        }
      }
    }
  }
}

// ---------------- split-K reduce: o = base + p0+p1+p2+p3 (4096x1024 f32) ----------------
__global__ __launch_bounds__(256) void reduce4_k(const float* __restrict__ base,
                                                 const float* __restrict__ p,
                                                 float* __restrict__ o) {
  long i = (long)blockIdx.x * 256 + threadIdx.x;  // float4 index
  const long PL = 4096L * 1024 / 4;               // plane stride in float4
  float4 b = ((const float4*)base)[i];
  float4 q0 = ((const float4*)p)[i];
  float4 q1 = ((const float4*)p)[i + PL];
  float4 q2 = ((const float4*)p)[i + 2 * PL];
  float4 q3 = ((const float4*)p)[i + 3 * PL];
  float4 r;
  r.x = b.x + q0.x + q1.x + q2.x + q3.x;
  r.y = b.y + q0.y + q1.y + q2.y + q3.y;
  r.z = b.z + q0.z + q1.z + q2.z + q3.z;
  r.w = b.w + q0.w + q1.w + q2.w + q3.w;
  ((float4*)o)[i] = r;
}

// ---------------- router: t += sum_a gelu(U)[.., a*512+p] ----------------
__global__ __launch_bounds__(256) void router_k(float* __restrict__ tb, const float* __restrict__ G) {
  int i = blockIdx.x * 256 + threadIdx.x;
  int r = i >> 7, pq = i & 127;
  float4 t = ((float4*)tb)[i];
#pragma unroll
  for (int a = 0; a < 4; ++a) {
    float4 g = *((const float4*)(G + (long)r * 2048 + a * 512) + pq);
    t.x += g.x; t.y += g.y; t.z += g.z; t.w += g.w;
  }
  ((float4*)tb)[i] = t;
}

// ---------------- chunk-parallel affine scan: h_t = f_t*h_{t-1} + u_t ----------------
__global__ void scan_chunk(const float* __restrict__ tb, const float* __restrict__ F,
                           float* __restrict__ abuf, float* __restrict__ ubuf) {
  int b = blockIdx.x >> 5, c = blockIdx.x & 31, pidx = threadIdx.x;
  const float* fp = F + ((long)(b * 2048 + c * 64) * 512) + pidx;
  const float* up = tb + ((long)(b * 2048 + c * 64) * 512) + pidx;
  float A = 1.f, U = 0.f;
#pragma unroll 8
  for (int s = 0; s < 64; ++s) {
    float f = fp[(long)s * 512], u = up[(long)s * 512];
    A = f * A;
    U = f * U + u;
  }
  abuf[(b * 32 + c) * 512 + pidx] = A;
  ubuf[(b * 32 + c) * 512 + pidx] = U;
}

__global__ void scan_combine(const float* __restrict__ abuf, const float* __restrict__ ubuf,
                             float* __restrict__ hstart) {
  int b = blockIdx.x, pidx = threadIdx.x;
  float h = 0.f;
  for (int c = 0; c < 32; ++c) {
    hstart[(b * 32 + c) * 512 + pidx] = h;
    h = abuf[(b * 32 + c) * 512 + pidx] * h + ubuf[(b * 32 + c) * 512 + pidx];
  }
}

__global__ void scan_apply(const float* __restrict__ tb, const float* __restrict__ F,
                           const float* __restrict__ hstart, u16* __restrict__ hbf) {
  int b = blockIdx.x >> 5, c = blockIdx.x & 31, pidx = threadIdx.x;
  const float* fp = F + ((long)(b * 2048 + c * 64) * 512) + pidx;
  const float* up = tb + ((long)(b * 2048 + c * 64) * 512) + pidx;
  u16* op = hbf + ((long)(b * 2048 + c * 64) * 512) + pidx;
  float h = hstart[(b * 32 + c) * 512 + pidx];
#pragma unroll 8
  for (int s = 0; s < 64; ++s) {
    float f = fp[(long)s * 512], u = up[(long)s * 512];
    h = f * h + u;
    op[(long)s * 512] = f2bf(h);
  }
}

extern "C" void kernel_launch(void* const* d_in, const int* in_sizes, int n_in,
                              void* d_out, int out_size, void* d_ws, size_t ws_size,
                              hipStream_t stream) {
  const float* x       = (const float*)d_in[0];
  const float* w_norm1 = (const float*)d_in[1];
  const float* w_toP   = (const float*)d_in[2];
  const float* w_emb   = (const float*)d_in[3];
  const float* w_f     = (const float*)d_in[4];
  const float* b_r     = (const float*)d_in[5];
  const float* c_r     = (const float*)d_in[6];
  const float* w_fromP = (const float*)d_in[7];
  const float* w_norm2 = (const float*)d_in[8];
  const float* w_fc1   = (const float*)d_in[9];
  const float* w_fc2   = (const float*)d_in[10];
  float* out = (float*)d_out;

  char* base = (char*)d_ws;
  size_t off = 0;
  auto alloc = [&](size_t bytes) {
    void* r = base + off;
    off += (bytes + 255) & ~(size_t)255;
    return r;
  };
  u16* W1T     = (u16*)alloc((size_t)3072 * 1024 * 2);
  u16* WfromPT = (u16*)alloc((size_t)1024 * 512 * 2);
  u16* Wfc1T   = (u16*)alloc((size_t)16384 * 1024 * 2);
  u16* Wfc2T   = (u16*)alloc((size_t)1024 * 16384 * 2);
  u16* BrT     = (u16*)alloc((size_t)128 * 512 * 2);
  u16* CrT     = (u16*)alloc((size_t)512 * 128 * 2);
  u16* h1      = (u16*)alloc((size_t)4096 * 1024 * 2);   // } h1..tt region (~68.5MB) is dead by
  float* G     = (float*)alloc((size_t)4096 * 2048 * 4); // } MLP time -> reused as 4 splitK
  float* F     = (float*)alloc((size_t)4096 * 512 * 4);  // } partial planes (67.1MB)
  float* tb    = (float*)alloc((size_t)4096 * 512 * 4);
  float* abuf  = (float*)alloc((size_t)2 * 32 * 512 * 4);
  float* ubuf  = (float*)alloc((size_t)2 * 32 * 512 * 4);
  float* hstart= (float*)alloc((size_t)2 * 32 * 512 * 4);
  u16* hbf     = (u16*)alloc((size_t)4096 * 512 * 2);
  u16* g1buf   = (u16*)alloc((size_t)4096 * 128 * 2);
  u16* tt      = (u16*)alloc((size_t)4096 * 512 * 2);
  float* xmid  = (float*)alloc((size_t)4096 * 1024 * 4);
  u16* h2      = (u16*)alloc((size_t)4096 * 1024 * 2);
  u16* a3      = (u16*)alloc((size_t)4096 * 8192 * 2);   // half-HID activation chunk
  float* part  = (float*)h1;                             // splitK partials overlay
  (void)ws_size; (void)in_sizes; (void)n_in; (void)out_size;

  dim3 tpb(32, 8);
  transpose_cvt<<<dim3(16, 32), tpb, 0, stream>>>(w_toP, W1T, 1024, 512, 1024);
  transpose_cvt<<<dim3(64, 32), tpb, 0, stream>>>(w_emb, W1T + (size_t)512 * 1024, 1024, 2048, 1024);
  transpose_cvt<<<dim3(16, 32), tpb, 0, stream>>>(w_f, W1T + (size_t)2560 * 1024, 1024, 512, 1024);
  transpose_cvt<<<dim3(32, 16), tpb, 0, stream>>>(w_fromP, WfromPT, 512, 1024, 512);
  transpose_cvt<<<dim3(512, 32), tpb, 0, stream>>>(w_fc1, Wfc1T, 1024, 16384, 1024);
  transpose_cvt<<<dim3(32, 512), tpb, 0, stream>>>(w_fc2, Wfc2T, 16384, 1024, 16384);
  hipMemsetAsync(BrT, 0, (size_t)128 * 512 * 2, stream);
  hipMemsetAsync(CrT, 0, (size_t)512 * 128 * 2, stream);
  transpose_cvt<<<dim3(2, 16), tpb, 0, stream>>>(b_r, BrT, 512, 64, 512);
  transpose_cvt<<<dim3(16, 2), tpb, 0, stream>>>(c_r, CrT, 64, 512, 128);

  // h1 = rmsnorm(x, w_norm1)
  rmsnorm_k<<<4096, 256, 0, stream>>>(x, w_norm1, h1);

  // fused GEMM1: [pre | gelu(U) | sigmoid(F)] = h1 @ [w_toP|w_emb|w_f]  (256^2 kernel)
  gemm256<EPI_ROUTE1><<<dim3(12, 16, 1), 512, 0, stream>>>(h1, W1T, nullptr, tb, G, F,
                                                           3072, 1024, 1024, 1024);
  router_k<<<2048, 256, 0, stream>>>(tb, G);

  // SSM scan -> h (bf16)
  scan_chunk<<<64, 512, 0, stream>>>(tb, F, abuf, ubuf);
  scan_combine<<<2, 512, 0, stream>>>(abuf, ubuf, hstart);
  scan_apply<<<64, 512, 0, stream>>>(tb, F, hstart, hbf);

  // low-rank: g1 = h @ b_r; t_tilde = t + g1 @ c_r; xmid = x + t_tilde @ w_fromP
  gemm_bt<EPI_BF16><<<dim3(1, 32), 256, 0, stream>>>(hbf, BrT, g1buf, nullptr, nullptr, nullptr, nullptr,
                                                     128, 512, 512, 512);
  gemm_bt<EPI_ADD_BF16><<<dim3(4, 32), 256, 0, stream>>>(g1buf, CrT, tt, nullptr, tb, nullptr, nullptr,
                                                         512, 128, 128, 128);
  gemm_bt<EPI_ADD_F32><<<dim3(8, 32), 256, 0, stream>>>(tt, WfromPT, nullptr, xmid, x, nullptr, nullptr,
                                                        1024, 512, 512, 512);
  // h2 = rmsnorm(xmid, w_norm2)
  rmsnorm_k<<<4096, 256, 0, stream>>>(xmid, w_norm2, h2);

  // MLP in 2 HID-chunks of 8192: a3 = gelu(h2 @ fc1_chunk); out = base + sum_bz(a3 @ fc2_chunk)
  for (int c = 0; c < 2; ++c) {
    gemm256<EPI_GELU_BF16><<<dim3(32, 16, 1), 512, 0, stream>>>(
        h2, Wfc1T + (size_t)c * 8192 * 1024, a3, nullptr, nullptr, nullptr,
        8192, 1024, 1024, 1024);
    gemm256<EPI_PART><<<dim3(4, 16, 4), 512, 0, stream>>>(
        a3, Wfc2T + (size_t)c * 8192, nullptr, part, nullptr, nullptr,
        1024, 8192, 8192, 16384);
    reduce4_k<<<4096, 256, 0, stream>>>((c == 0 ? xmid : out), part, out);
  }
}

// Round 4
// 537.576 us; speedup vs baseline: 1.3866x; 1.2252x over previous
//
#include <hip/hip_runtime.h>

typedef unsigned short u16;
typedef __bf16 bf16x8 __attribute__((ext_vector_type(8)));
typedef float f32x4 __attribute__((ext_vector_type(4)));
typedef int i32x4 __attribute__((ext_vector_type(4)));

__device__ inline u16 f2bf(float f) {
  union { float f; unsigned u; } v; v.f = f;
  unsigned u = v.u;
  unsigned r = (u + 0x7FFFu + ((u >> 16) & 1u)) >> 16;
  return (u16)r;
}

__device__ inline float gelu_f(float x) {
  // tanh approximation (jax.nn.gelu default), overflow-safe tanh
  float t = 0.7978845608028654f * (x + 0.044715f * x * x * x);
  float a = __expf(-2.f * fabsf(t));
  float th = (1.f - a) / (1.f + a);
  th = copysignf(th, t);
  return 0.5f * x * (1.f + th);
}
__device__ inline float sigmoid_f(float x) { return 1.f / (1.f + __expf(-x)); }

// async global->LDS, 16B per lane; LDS dest is wave-uniform base + lane*16 (m104)
__device__ __forceinline__ void gld16(const u16* g, u16* l) {
  __builtin_amdgcn_global_load_lds((const __attribute__((address_space(1))) void*)g,
                                   (__attribute__((address_space(3))) void*)l, 16, 0, 0);
}
__device__ __forceinline__ bf16x8 ld_frag(const u16* p) {
  return __builtin_bit_cast(bf16x8, *(const i32x4*)p);
}

// ---------------- transpose + fp32->bf16 convert: out[c][r] = in[r][c] ----------------
__global__ void transpose_cvt(const float* __restrict__ in, u16* __restrict__ out,
                              int R, int C, int ldout) {
  __shared__ float tile[32][33];
  int c0 = blockIdx.x * 32, r0 = blockIdx.y * 32;
  int tx = threadIdx.x, ty = threadIdx.y;
#pragma unroll
  for (int i = 0; i < 32; i += 8) {
    int r = r0 + ty + i, c = c0 + tx;
    tile[ty + i][tx] = (r < R && c < C) ? in[(long)r * C + c] : 0.f;
  }
  __syncthreads();
#pragma unroll
  for (int i = 0; i < 32; i += 8) {
    int cc = c0 + ty + i, rr = r0 + tx;
    if (cc < C && rr < R) out[(long)cc * ldout + rr] = f2bf(tile[tx][ty + i]);
  }
}

// ---------------- RMSNorm (D=1024 fixed), fp32 in -> bf16 out ----------------
__global__ __launch_bounds__(256) void rmsnorm_k(const float* __restrict__ x,
                                                 const float* __restrict__ w,
                                                 u16* __restrict__ out) {
  int row = blockIdx.x;
  int tid = threadIdx.x;
  const float4* xv = (const float4*)(x + (long)row * 1024);
  float4 v = xv[tid];
  float ss = v.x * v.x + v.y * v.y + v.z * v.z + v.w * v.w;
#pragma unroll
  for (int off = 32; off > 0; off >>= 1) ss += __shfl_down(ss, off);
  __shared__ float red[4];
  if ((tid & 63) == 0) red[tid >> 6] = ss;
  __syncthreads();
  float tot = red[0] + red[1] + red[2] + red[3];
  float scale = rsqrtf(tot * (1.f / 1024.f) + 1e-6f);
  const float4* wv4 = (const float4*)w;
  float4 wv = wv4[tid];
  ushort4 o;
  o.x = f2bf(v.x * wv.x * scale);
  o.y = f2bf(v.y * wv.y * scale);
  o.z = f2bf(v.z * wv.z * scale);
  o.w = f2bf(v.w * wv.w * scale);
  *((ushort4*)(out + (long)row * 1024) + tid) = o;
}

#define EPI_BF16 0
#define EPI_ROUTE1 1
#define EPI_ADD_BF16 2
#define EPI_ADD_F32 3
#define EPI_GELU_BF16 4
#define EPI_PART 5

// ============ 256x256x64 counted-vmcnt 4-phase pipelined GEMM (T2+T3+T4+T5) ============
// C = A(MxK) * Bt(NxK)^T. 512 thr (8 waves, 2Mx4N). LDS: 2 bufs x (A,B) x 4 segs of
// [128 rows][32 k] bf16 (8 KiB each). Per tile: 4 phases, each = {ds_read quadrant frags |
// stage 2 segs of tile t+1 into buf^1 | 16 MFMA}. Waits: vmcnt(4)+s_barrier at ph0/ph2
// ONLY (kh0/kh1 arrival) -- loads never drain to 0 in the main loop (T4).
// Bank-conflict fix via source-side XOR swizzle (rule #21): stage thread t fetches global
// 16B-chunk (t&3)^((t>>3)&3); reads use chunk (lane>>4)^((lane15>>1)&3). Involution => exact.
template <int EPI>
__global__ __launch_bounds__(512, 2) void gemm256(
    const u16* __restrict__ A, const u16* __restrict__ Bt,
    u16* __restrict__ obf, float* __restrict__ of32,
    float* __restrict__ og, float* __restrict__ ofl,
    int N, int K, int lda, int ldb) {
  __shared__ __align__(16) u16 sA[2][16384];
  __shared__ __align__(16) u16 sB[2][16384];
  const int tid = threadIdx.x;
  const int lane = tid & 63;
  const int wave = tid >> 6;
  const int wm = wave >> 2, wn = wave & 3;
  const int lane15 = lane & 15;

  // XCD-aware swizzle (T1); identity if nwg%8!=0
  const int gx = gridDim.x, gy = gridDim.y, gz = gridDim.z;
  const int nwg = gx * gy * gz;
  int orig = (blockIdx.z * gy + blockIdx.y) * gx + blockIdx.x;
  int id = ((nwg & 7) == 0) ? ((orig & 7) * (nwg >> 3) + (orig >> 3)) : orig;
  const int bx = id % gx;
  const int by = (id / gx) % gy;
  const int bz = id / (gx * gy);
  const int bm0 = by * 256, bn0 = bx * 256;
  const int kper = K / gz, koff = bz * kper;

  f32x4 acc[8][4];
  f32x4 zero = {0.f, 0.f, 0.f, 0.f};
#pragma unroll
  for (int m = 0; m < 8; ++m)
#pragma unroll
    for (int n = 0; n < 4; ++n) acc[m][n] = zero;

  // staging: thread t covers seg-slot t -> (row = t>>2, lds chunk = t&3) holding global
  // chunk (t&3)^((t>>3)&3). HW writes lds base + lane*16.
  const int grow = tid >> 2;
  const int gck = ((tid & 3) ^ ((tid >> 3) & 3)) << 3;  // u16 units
  const u16* ag = A + (long)(bm0 + grow) * lda + koff + gck;
  const u16* bg = Bt + (long)(bn0 + grow) * ldb + koff + gck;
  const long a128 = (long)128 * lda, b128 = (long)128 * ldb;
  const int wofs = wave << 9;  // wave*512 u16 = 1024 B per-wave slice

  // read-side swizzled chunk offset (u16): global chunk lane>>4 lives at lds chunk ^ swz(row)
  const int coff = (((lane >> 4) ^ ((lane15 >> 1) & 3)) << 3);
  const int rbrow = (wn & 1) * 64 + lane15;  // B within-seg row base; B seg-half = wn>>1
  const int bsegh = (wn >> 1) * 2;           // *4096 later: seg index base for B = (wn>>1)*2+kk

  const int nk = kper >> 6;

  // prologue: tile 0 -> buf0, order kh0(A,A,B,B) then kh1(A,A,B,B)  [vmcnt count order]
  gld16(ag, &sA[0][0 * 4096 + wofs]);
  gld16(ag + a128, &sA[0][2 * 4096 + wofs]);
  gld16(bg, &sB[0][0 * 4096 + wofs]);
  gld16(bg + b128, &sB[0][2 * 4096 + wofs]);
  gld16(ag + 32, &sA[0][1 * 4096 + wofs]);
  gld16(ag + a128 + 32, &sA[0][3 * 4096 + wofs]);
  gld16(bg + 32, &sB[0][1 * 4096 + wofs]);
  gld16(bg + b128 + 32, &sB[0][3 * 4096 + wofs]);

  bf16x8 av[4], bv[4];
#define DSRD_B(kk)                                                                   \
  _Pragma("unroll") for (int n = 0; n < 4; ++n)                                      \
      bv[n] = ld_frag(rB + (bsegh + kk) * 4096 + (rbrow + n * 16) * 32 + coff);
#define DSRD_A(kk, mh)                                                               \
  _Pragma("unroll") for (int m = 0; m < 4; ++m)                                      \
      av[m] = ld_frag(rA + (wm * 2 + kk) * 4096 + (mh * 64 + m * 16 + lane15) * 32 + coff);
#define MFMA16(mh)                                                                   \
  __builtin_amdgcn_s_setprio(1);                                                     \
  _Pragma("unroll") for (int m = 0; m < 4; ++m)                                      \
      _Pragma("unroll") for (int n = 0; n < 4; ++n)                                  \
          acc[mh * 4 + m][n] =                                                       \
              __builtin_amdgcn_mfma_f32_16x16x32_bf16(av[m], bv[n], acc[mh * 4 + m][n], 0, 0, 0); \
  __builtin_amdgcn_s_setprio(0);
#define WAIT4()                                     \
  asm volatile("s_waitcnt vmcnt(4)" ::: "memory");  \
  __builtin_amdgcn_s_barrier();                     \
  asm volatile("" ::: "memory")
#define WAIT0()                                     \
  asm volatile("s_waitcnt vmcnt(0)" ::: "memory");  \
  __builtin_amdgcn_s_barrier();                     \
  asm volatile("" ::: "memory")

  int p = 0;
  for (int t = 0; t < nk - 1; ++t) {
    const u16* agn = ag + (long)(t + 1) * 64;
    const u16* bgn = bg + (long)(t + 1) * 64;
    u16* dA = &sA[p ^ 1][0];
    u16* dB = &sB[p ^ 1][0];
    const u16* rA = &sA[p][0];
    const u16* rB = &sB[p][0];
    // ---- ph0: kk0, mh0 (kh0 of tile t guaranteed landed) ----
    WAIT4();
    DSRD_B(0);
    DSRD_A(0, 0);
    gld16(agn, dA + 0 * 4096 + wofs);
    gld16(agn + a128, dA + 2 * 4096 + wofs);
    MFMA16(0);
    // ---- ph1: kk0, mh1 ----
    DSRD_A(0, 1);
    gld16(bgn, dB + 0 * 4096 + wofs);
    gld16(bgn + b128, dB + 2 * 4096 + wofs);
    MFMA16(1);
    // ---- ph2: kk1, mh0 (kh1 of tile t landed) ----
    WAIT4();
    DSRD_B(1);
    DSRD_A(1, 0);
    gld16(agn + 32, dA + 1 * 4096 + wofs);
    gld16(agn + a128 + 32, dA + 3 * 4096 + wofs);
    MFMA16(0);
    // ---- ph3: kk1, mh1 ----
    DSRD_A(1, 1);
    gld16(bgn + 32, dB + 1 * 4096 + wofs);
    gld16(bgn + b128 + 32, dB + 3 * 4096 + wofs);
    MFMA16(1);
    p ^= 1;
  }
  {  // ---- final tile: no staging; kh1's 4 loads are the only outstanding ones ----
    const u16* rA = &sA[p][0];
    const u16* rB = &sB[p][0];
    WAIT4();
    DSRD_B(0);
    DSRD_A(0, 0);
    MFMA16(0);
    DSRD_A(0, 1);
    MFMA16(1);
    WAIT0();
    DSRD_B(1);
    DSRD_A(1, 0);
    MFMA16(0);
    DSRD_A(1, 1);
    MFMA16(1);
  }
#undef DSRD_B
#undef DSRD_A
#undef MFMA16
#undef WAIT4
#undef WAIT0

  // epilogue: C/D layout col=lane&15, row=(lane>>4)*4+reg (m89-verified)
#pragma unroll
  for (int M = 0; M < 8; ++M) {
    int row_b = bm0 + wm * 128 + M * 16 + ((lane >> 4) << 2);
#pragma unroll
    for (int n = 0; n < 4; ++n) {
      int col = bn0 + wn * 64 + n * 16 + lane15;
#pragma unroll
      for (int j = 0; j < 4; ++j) {
        int row = row_b + j;
        float v = acc[M][n][j];
        if constexpr (EPI == EPI_GELU_BF16) {
          obf[(long)row * N + col] = f2bf(gelu_f(v));
        } else if constexpr (EPI == EPI_ROUTE1) {
          if (col < 512) of32[(long)row * 512 + col] = v;                       // pre_path -> t
          else if (col < 2560) og[(long)row * 2048 + (col - 512)] = gelu_f(v);  // gelu(U)
          else ofl[(long)row * 512 + (col - 2560)] = sigmoid_f(v);              // F gate
        } else {  // EPI_PART: split-K partial plane bz (N==1024)
          of32[(long)bz * (4096L * 1024) + (long)row * N + col] = v;
        }
      }
    }
  }
}

// ---------------- generic bf16 GEMM, 128x128x64 tiles, reg-staged (round-1, known-good) ----
template <int EPI>
__global__ __launch_bounds__(256) void gemm_bt(
    const u16* __restrict__ A, const u16* __restrict__ Bt,
    u16* __restrict__ obf, float* __restrict__ of32, const float* __restrict__ add,
    float* __restrict__ og, float* __restrict__ ofl,
    int N, int K, int lda, int ldb) {
  __shared__ __align__(16) u16 As[128 * 64];
  __shared__ __align__(16) u16 Bs[128 * 64];
  const int tid = threadIdx.x;
  const int lane = tid & 63;
  const int wave = tid >> 6;
  const int wm = wave >> 1, wn = wave & 1;
  const int bm0 = blockIdx.y * 128, bn0 = blockIdx.x * 128;

  f32x4 acc[4][4];
  f32x4 zero = {0.f, 0.f, 0.f, 0.f};
#pragma unroll
  for (int m = 0; m < 4; ++m)
#pragma unroll
    for (int n = 0; n < 4; ++n) acc[m][n] = zero;

  i32x4 ra[4], rb[4];
  int srow[4], schk[4];
#pragma unroll
  for (int i = 0; i < 4; ++i) {
    int s = tid + 256 * i;
    srow[i] = s >> 3;
    schk[i] = s & 7;
  }
#pragma unroll
  for (int i = 0; i < 4; ++i) {
    ra[i] = *(const i32x4*)(A + (bm0 + srow[i]) * lda + schk[i] * 8);
    rb[i] = *(const i32x4*)(Bt + (bn0 + srow[i]) * ldb + schk[i] * 8);
  }

  const int nk = K >> 6;
  for (int t = 0; t < nk; ++t) {
#pragma unroll
    for (int i = 0; i < 4; ++i) {
      *(i32x4*)&As[srow[i] * 64 + ((schk[i] ^ (srow[i] & 7)) << 3)] = ra[i];
      *(i32x4*)&Bs[srow[i] * 64 + ((schk[i] ^ (srow[i] & 7)) << 3)] = rb[i];
    }
    __syncthreads();
    if (t + 1 < nk) {
      int k0 = (t + 1) << 6;
#pragma unroll
      for (int i = 0; i < 4; ++i) {
        ra[i] = *(const i32x4*)(A + (bm0 + srow[i]) * lda + k0 + schk[i] * 8);
        rb[i] = *(const i32x4*)(Bt + (bn0 + srow[i]) * ldb + k0 + schk[i] * 8);
      }
    }
#pragma unroll
    for (int kk = 0; kk < 2; ++kk) {
      bf16x8 av[4], bv[4];
#pragma unroll
      for (int m = 0; m < 4; ++m) {
        int r = wm * 64 + m * 16 + (lane & 15);
        int c = kk * 4 + (lane >> 4);
        av[m] = __builtin_bit_cast(bf16x8, *(const i32x4*)&As[r * 64 + ((c ^ (r & 7)) << 3)]);
      }
#pragma unroll
      for (int n = 0; n < 4; ++n) {
        int r = wn * 64 + n * 16 + (lane & 15);
        int c = kk * 4 + (lane >> 4);
        bv[n] = __builtin_bit_cast(bf16x8, *(const i32x4*)&Bs[r * 64 + ((c ^ (r & 7)) << 3)]);
      }
#pragma unroll
      for (int m = 0; m < 4; ++m)
#pragma unroll
        for (int n = 0; n < 4; ++n)
          acc[m][n] = __builtin_amdgcn_mfma_f32_16x16x32_bf16(av[m], bv[n], acc[m][n], 0, 0, 0);
    }
    __syncthreads();
  }

#pragma unroll
  for (int m = 0; m < 4; ++m) {
    int row_b = bm0 + wm * 64 + m * 16 + ((lane >> 4) << 2);
#pragma unroll
    for (int n = 0; n < 4; ++n) {
      int col = bn0 + wn * 64 + n * 16 + (lane & 15);
#pragma unroll
      for (int j = 0; j < 4; ++j) {
        int row = row_b + j;
        float v = acc[m][n][j];
        if constexpr (EPI == EPI_BF16) {
          obf[(long)row * N + col] = f2bf(v);
        } else if constexpr (EPI == EPI_ADD_BF16) {
          long idx = (long)row * N + col;
          obf[idx] = f2bf(add[idx] + v);
        } else if constexpr (EPI == EPI_ADD_F32) {
          long idx = (long)row * N + col;
          of32[idx] = add[idx] + v;
        }
      }
    }
  }
}

// ---------------- split-K reduce: o = base + p0+p1+p2+p3 (4096x1024 f32) ----------------
__global__ __launch_bounds__(256) void reduce4_k(const float* __restrict__ base,
                                                 const float* __restrict__ p,
                                                 float* __restrict__ o) {
  long i = (long)blockIdx.x * 256 + threadIdx.x;  // float4 index
  const long PL = 4096L * 1024 / 4;               // plane stride in float4
  float4 b = ((const float4*)base)[i];
  float4 q0 = ((const float4*)p)[i];
  float4 q1 = ((const float4*)p)[i + PL];
  float4 q2 = ((const float4*)p)[i + 2 * PL];
  float4 q3 = ((const float4*)p)[i + 3 * PL];
  float4 r;
  r.x = b.x + q0.x + q1.x + q2.x + q3.x;
  r.y = b.y + q0.y + q1.y + q2.y + q3.y;
  r.z = b.z + q0.z + q1.z + q2.z + q3.z;
  r.w = b.w + q0.w + q1.w + q2.w + q3.w;
  ((float4*)o)[i] = r;
}

// ---------------- router: t += sum_a gelu(U)[.., a*512+p] ----------------
__global__ __launch_bounds__(256) void router_k(float* __restrict__ tb, const float* __restrict__ G) {
  int i = blockIdx.x * 256 + threadIdx.x;
  int r = i >> 7, pq = i & 127;
  float4 t = ((float4*)tb)[i];
#pragma unroll
  for (int a = 0; a < 4; ++a) {
    float4 g = *((const float4*)(G + (long)r * 2048 + a * 512) + pq);
    t.x += g.x; t.y += g.y; t.z += g.z; t.w += g.w;
  }
  ((float4*)tb)[i] = t;
}

// ---------------- chunk-parallel affine scan: h_t = f_t*h_{t-1} + u_t ----------------
__global__ void scan_chunk(const float* __restrict__ tb, const float* __restrict__ F,
                           float* __restrict__ abuf, float* __restrict__ ubuf) {
  int b = blockIdx.x >> 5, c = blockIdx.x & 31, pidx = threadIdx.x;
  const float* fp = F + ((long)(b * 2048 + c * 64) * 512) + pidx;
  const float* up = tb + ((long)(b * 2048 + c * 64) * 512) + pidx;
  float A = 1.f, U = 0.f;
#pragma unroll 8
  for (int s = 0; s < 64; ++s) {
    float f = fp[(long)s * 512], u = up[(long)s * 512];
    A = f * A;
    U = f * U + u;
  }
  abuf[(b * 32 + c) * 512 + pidx] = A;
  ubuf[(b * 32 + c) * 512 + pidx] = U;
}

__global__ void scan_combine(const float* __restrict__ abuf, const float* __restrict__ ubuf,
                             float* __restrict__ hstart) {
  int b = blockIdx.x, pidx = threadIdx.x;
  float h = 0.f;
  for (int c = 0; c < 32; ++c) {
    hstart[(b * 32 + c) * 512 + pidx] = h;
    h = abuf[(b * 32 + c) * 512 + pidx] * h + ubuf[(b * 32 + c) * 512 + pidx];
  }
}

__global__ void scan_apply(const float* __restrict__ tb, const float* __restrict__ F,
                           const float* __restrict__ hstart, u16* __restrict__ hbf) {
  int b = blockIdx.x >> 5, c = blockIdx.x & 31, pidx = threadIdx.x;
  const float* fp = F + ((long)(b * 2048 + c * 64) * 512) + pidx;
  const float* up = tb + ((long)(b * 2048 + c * 64) * 512) + pidx;
  u16* op = hbf + ((long)(b * 2048 + c * 64) * 512) + pidx;
  float h = hstart[(b * 32 + c) * 512 + pidx];
#pragma unroll 8
  for (int s = 0; s < 64; ++s) {
    float f = fp[(long)s * 512], u = up[(long)s * 512];
    h = f * h + u;
    op[(long)s * 512] = f2bf(h);
  }
}

extern "C" void kernel_launch(void* const* d_in, const int* in_sizes, int n_in,
                              void* d_out, int out_size, void* d_ws, size_t ws_size,
                              hipStream_t stream) {
  const float* x       = (const float*)d_in[0];
  const float* w_norm1 = (const float*)d_in[1];
  const float* w_toP   = (const float*)d_in[2];
  const float* w_emb   = (const float*)d_in[3];
  const float* w_f     = (const float*)d_in[4];
  const float* b_r     = (const float*)d_in[5];
  const float* c_r     = (const float*)d_in[6];
  const float* w_fromP = (const float*)d_in[7];
  const float* w_norm2 = (const float*)d_in[8];
  const float* w_fc1   = (const float*)d_in[9];
  const float* w_fc2   = (const float*)d_in[10];
  float* out = (float*)d_out;

  char* base = (char*)d_ws;
  size_t off = 0;
  auto alloc = [&](size_t bytes) {
    void* r = base + off;
    off += (bytes + 255) & ~(size_t)255;
    return r;
  };
  u16* W1T     = (u16*)alloc((size_t)3072 * 1024 * 2);
  u16* WfromPT = (u16*)alloc((size_t)1024 * 512 * 2);
  u16* Wfc1T   = (u16*)alloc((size_t)16384 * 1024 * 2);
  u16* Wfc2T   = (u16*)alloc((size_t)1024 * 16384 * 2);
  u16* BrT     = (u16*)alloc((size_t)128 * 512 * 2);
  u16* CrT     = (u16*)alloc((size_t)512 * 128 * 2);
  u16* h1      = (u16*)alloc((size_t)4096 * 1024 * 2);   // } h1..tt region (~68.5MB) is dead by
  float* G     = (float*)alloc((size_t)4096 * 2048 * 4); // } MLP time -> reused as 4 splitK
  float* F     = (float*)alloc((size_t)4096 * 512 * 4);  // } partial planes (67.1MB)
  float* tb    = (float*)alloc((size_t)4096 * 512 * 4);
  float* abuf  = (float*)alloc((size_t)2 * 32 * 512 * 4);
  float* ubuf  = (float*)alloc((size_t)2 * 32 * 512 * 4);
  float* hstart= (float*)alloc((size_t)2 * 32 * 512 * 4);
  u16* hbf     = (u16*)alloc((size_t)4096 * 512 * 2);
  u16* g1buf   = (u16*)alloc((size_t)4096 * 128 * 2);
  u16* tt      = (u16*)alloc((size_t)4096 * 512 * 2);
  float* xmid  = (float*)alloc((size_t)4096 * 1024 * 4);
  u16* h2      = (u16*)alloc((size_t)4096 * 1024 * 2);
  u16* a3      = (u16*)alloc((size_t)4096 * 8192 * 2);   // half-HID activation chunk
  float* part  = (float*)h1;                             // splitK partials overlay
  (void)ws_size; (void)in_sizes; (void)n_in; (void)out_size;

  dim3 tpb(32, 8);
  transpose_cvt<<<dim3(16, 32), tpb, 0, stream>>>(w_toP, W1T, 1024, 512, 1024);
  transpose_cvt<<<dim3(64, 32), tpb, 0, stream>>>(w_emb, W1T + (size_t)512 * 1024, 1024, 2048, 1024);
  transpose_cvt<<<dim3(16, 32), tpb, 0, stream>>>(w_f, W1T + (size_t)2560 * 1024, 1024, 512, 1024);
  transpose_cvt<<<dim3(32, 16), tpb, 0, stream>>>(w_fromP, WfromPT, 512, 1024, 512);
  transpose_cvt<<<dim3(512, 32), tpb, 0, stream>>>(w_fc1, Wfc1T, 1024, 16384, 1024);
  transpose_cvt<<<dim3(32, 512), tpb, 0, stream>>>(w_fc2, Wfc2T, 16384, 1024, 16384);
  hipMemsetAsync(BrT, 0, (size_t)128 * 512 * 2, stream);
  hipMemsetAsync(CrT, 0, (size_t)512 * 128 * 2, stream);
  transpose_cvt<<<dim3(2, 16), tpb, 0, stream>>>(b_r, BrT, 512, 64, 512);
  transpose_cvt<<<dim3(16, 2), tpb, 0, stream>>>(c_r, CrT, 64, 512, 128);

  // h1 = rmsnorm(x, w_norm1)
  rmsnorm_k<<<4096, 256, 0, stream>>>(x, w_norm1, h1);

  // fused GEMM1: [pre | gelu(U) | sigmoid(F)] = h1 @ [w_toP|w_emb|w_f]
  gemm256<EPI_ROUTE1><<<dim3(12, 16, 1), 512, 0, stream>>>(h1, W1T, nullptr, tb, G, F,
                                                           3072, 1024, 1024, 1024);
  router_k<<<2048, 256, 0, stream>>>(tb, G);

  // SSM scan -> h (bf16)
  scan_chunk<<<64, 512, 0, stream>>>(tb, F, abuf, ubuf);
  scan_combine<<<2, 512, 0, stream>>>(abuf, ubuf, hstart);
  scan_apply<<<64, 512, 0, stream>>>(tb, F, hstart, hbf);

  // low-rank: g1 = h @ b_r; t_tilde = t + g1 @ c_r; xmid = x + t_tilde @ w_fromP
  gemm_bt<EPI_BF16><<<dim3(1, 32), 256, 0, stream>>>(hbf, BrT, g1buf, nullptr, nullptr, nullptr, nullptr,
                                                     128, 512, 512, 512);
  gemm_bt<EPI_ADD_BF16><<<dim3(4, 32), 256, 0, stream>>>(g1buf, CrT, tt, nullptr, tb, nullptr, nullptr,
                                                         512, 128, 128, 128);
  gemm_bt<EPI_ADD_F32><<<dim3(8, 32), 256, 0, stream>>>(tt, WfromPT, nullptr, xmid, x, nullptr, nullptr,
                                                        1024, 512, 512, 512);
  // h2 = rmsnorm(xmid, w_norm2)
  rmsnorm_k<<<4096, 256, 0, stream>>>(xmid, w_norm2, h2);

  // MLP in 2 HID-chunks of 8192: a3 = gelu(h2 @ fc1_chunk); out = base + sum_bz(a3 @ fc2_chunk)
  for (int c = 0; c < 2; ++c) {
    gemm256<EPI_GELU_BF16><<<dim3(32, 16, 1), 512, 0, stream>>>(
        h2, Wfc1T + (size_t)c * 8192 * 1024, a3, nullptr, nullptr, nullptr,
        8192, 1024, 1024, 1024);
    gemm256<EPI_PART><<<dim3(4, 16, 4), 512, 0, stream>>>(
        a3, Wfc2T + (size_t)c * 8192, nullptr, part, nullptr, nullptr,
        1024, 8192, 8192, 16384);
    reduce4_k<<<4096, 256, 0, stream>>>((c == 0 ? xmid : out), part, out);
  }
}